// Round 4
// baseline (80.262 us; speedup 1.0000x reference)
//
#include <hip/hip_runtime.h>

#define NB   8
#define CIN  32
#define HH   28
#define WW   28
#define OC   64
#define HWSZ (HH*WW)            // 784
#define TOTAL (NB*OC*HWSZ)      // 401408
#define CNT  (NB*HWSZ)          // 6272 elements per channel for BN stats

#define KSPLIT 4
#define KH     (CIN/KSPLIT)     // 8 input channels per block
#define TROWS  6                // rows h0-1 .. h0+4
#define TCOLS  30
#define TSZ    (KH*TROWS*TCOLS) // 1440 floats = 5.76 KB

#define CPW    4                // output channels per wave; 4 waves -> 16 ch/block
// grid: n(8) x rowquad(7) x chgrp(4) x ksplit(4) = 896 blocks

__global__ __launch_bounds__(256) void adder_kernel(
    const float* __restrict__ x, const float* __restrict__ Wt,
    float* __restrict__ rawp)    // KSPLIT partial buffers of TOTAL floats each
{
    __shared__ float xs[TSZ];
    const int t     = threadIdx.x;
    const int bid   = blockIdx.x;
    const int ks    = bid & 3;
    const int chgrp = (bid >> 2) & 3;
    const int rq    = (bid >> 4) % 7;
    const int n     = bid / (16 * 7);
    const int h0    = rq * 4;            // block covers rows h0..h0+3
    const int c0    = ks * KH;

    // ---- stage x: channels c0..c0+7, rows h0-1..h0+4, cols -1..28, zero-pad ----
    for (int i = t; i < TSZ; i += 256) {
        int cc  = i / (TROWS*TCOLS);
        int rem = i % (TROWS*TCOLS);
        int r   = rem / TCOLS;
        int col = rem % TCOLS;
        int hh  = h0 - 1 + r;
        int ww  = col - 1;
        float v = 0.0f;
        if (hh >= 0 && hh < HH && ww >= 0 && ww < WW)
            v = x[((n*CIN + (c0+cc))*HH + hh)*WW + ww];
        xs[i] = v;
    }
    __syncthreads();

    const int lane = t & 63;
    const int g    = __builtin_amdgcn_readfirstlane(t >> 6);  // wave id, uniform
    const int rg   = lane >> 5;          // 0,1: which pixel-row-pair
    const int pl   = lane & 31;
    const bool valid = pl < WW;
    const int pw   = valid ? pl : 0;
    const int o_base = chgrp*16 + g*CPW;

    // each lane: 2 vertically-adjacent pixels (rows h0+2rg, h0+2rg+1)
    float acc[2][CPW];
    #pragma unroll
    for (int pix = 0; pix < 2; ++pix)
        #pragma unroll
        for (int oo = 0; oo < CPW; ++oo) acc[pix][oo] = 0.0f;

    #pragma unroll
    for (int cc = 0; cc < KH; ++cc) {
        // 4 patch rows x 3 cols, shared by both pixels
        float xr[4][3];
        const int b0 = (cc*TROWS + 2*rg)*TCOLS + pw;
        #pragma unroll
        for (int dr = 0; dr < 4; ++dr)
            #pragma unroll
            for (int dc = 0; dc < 3; ++dc)
                xr[dr][dc] = xs[b0 + dr*TCOLS + dc];

        #pragma unroll
        for (int oo = 0; oo < CPW; ++oo) {
            const float* wp = Wt + ((o_base + oo)*CIN + (c0 + cc))*9; // uniform -> s_load
            #pragma unroll
            for (int dr = 0; dr < 3; ++dr)
                #pragma unroll
                for (int dc = 0; dc < 3; ++dc) {
                    float w = wp[dr*3+dc];
                    acc[0][oo] += __builtin_fabsf(xr[dr][dc]   - w);
                    acc[1][oo] += __builtin_fabsf(xr[dr+1][dc] - w);
                }
        }
    }

    // ---- write partial sums ----
    if (valid) {
        float* rawh = rawp + ks * TOTAL;
        #pragma unroll
        for (int pix = 0; pix < 2; ++pix) {
            const int hh = h0 + 2*rg + pix;
            #pragma unroll
            for (int oo = 0; oo < CPW; ++oo)
                rawh[((n*OC + o_base + oo)*HH + hh)*WW + pw] = -acc[pix][oo];
        }
    }
}

// one block per output channel: combine 4 partials, reduce sum/sumsq (double),
// emit per-channel scale/shift
__global__ __launch_bounds__(256) void stats_kernel(
    const float* __restrict__ rawp,
    const float* __restrict__ gamma, const float* __restrict__ beta,
    float* __restrict__ sc)
{
    const int o = blockIdx.x;
    const int t = threadIdx.x;
    const float4* r0 = (const float4*)rawp;
    const float4* r1 = (const float4*)(rawp + TOTAL);
    const float4* r2 = (const float4*)(rawp + 2*TOTAL);
    const float4* r3 = (const float4*)(rawp + 3*TOTAL);
    double s = 0.0, s2 = 0.0;
    for (int i4 = t; i4 < CNT/4; i4 += 256) {     // 1568 float4s per channel
        int nn  = i4 / (HWSZ/4);
        int pos = i4 % (HWSZ/4);
        int idx = (nn*OC + o)*(HWSZ/4) + pos;
        float4 a = r0[idx], b = r1[idx], c = r2[idx], d = r3[idx];
        float vx = (a.x + b.x) + (c.x + d.x);
        float vy = (a.y + b.y) + (c.y + d.y);
        float vz = (a.z + b.z) + (c.z + d.z);
        float vw = (a.w + b.w) + (c.w + d.w);
        s  += (double)vx + (double)vy + (double)vz + (double)vw;
        s2 += (double)vx*vx + (double)vy*vy + (double)vz*vz + (double)vw*vw;
    }
    #pragma unroll
    for (int off = 32; off >= 1; off >>= 1) {
        s  += __shfl_xor(s,  off, 64);
        s2 += __shfl_xor(s2, off, 64);
    }
    __shared__ double ls[4], ls2[4];
    const int lane = t & 63, w = t >> 6;
    if (lane == 0) { ls[w] = s; ls2[w] = s2; }
    __syncthreads();
    if (t == 0) {
        double S  = ls[0] + ls[1] + ls[2] + ls[3];
        double S2 = ls2[0] + ls2[1] + ls2[2] + ls2[3];
        double mean = S * (1.0 / CNT);
        double var  = S2 * (1.0 / CNT) - mean * mean;
        double inv  = 1.0 / sqrt(var + 1e-5);
        double scl  = (double)gamma[o] * inv;
        sc[o]       = (float)scl;
        sc[64 + o]  = (float)((double)beta[o] - mean * scl);
    }
}

// y = (r0+r1+r2+r3)*sc[o] + sh[o], float4-vectorized
__global__ __launch_bounds__(256) void bn_kernel(
    const float* __restrict__ rawp, const float* __restrict__ sc,
    float* __restrict__ out)
{
    int i4 = blockIdx.x * 256 + threadIdx.x;   // float4 index
    if (i4 >= TOTAL/4) return;
    int o = (i4 / (HWSZ/4)) & (OC - 1);
    float s = sc[o];
    float b = sc[64 + o];
    float4 a0 = ((const float4*)rawp)[i4];
    float4 a1 = ((const float4*)(rawp + TOTAL))[i4];
    float4 a2 = ((const float4*)(rawp + 2*TOTAL))[i4];
    float4 a3 = ((const float4*)(rawp + 3*TOTAL))[i4];
    float4 v;
    v.x = ((a0.x + a1.x) + (a2.x + a3.x)) * s + b;
    v.y = ((a0.y + a1.y) + (a2.y + a3.y)) * s + b;
    v.z = ((a0.z + a1.z) + (a2.z + a3.z)) * s + b;
    v.w = ((a0.w + a1.w) + (a2.w + a3.w)) * s + b;
    ((float4*)out)[i4] = v;
}

extern "C" void kernel_launch(void* const* d_in, const int* in_sizes, int n_in,
                              void* d_out, int out_size, void* d_ws, size_t ws_size,
                              hipStream_t stream) {
    const float* x     = (const float*)d_in[0];
    const float* Wt    = (const float*)d_in[1];
    const float* gamma = (const float*)d_in[2];
    const float* beta  = (const float*)d_in[3];
    float* out = (float*)d_out;

    // ws layout: [0,512) sc (128 floats); [4096, 4096+KSPLIT*TOTAL*4) raw partials
    float* sc   = (float*)d_ws;
    float* rawp = (float*)((char*)d_ws + 4096);

    adder_kernel<<<NB*7*4*KSPLIT, 256, 0, stream>>>(x, Wt, rawp);
    stats_kernel<<<OC, 256, 0, stream>>>(rawp, gamma, beta, sc);
    bn_kernel<<<(TOTAL/4 + 255) / 256, 256, 0, stream>>>(rawp, sc, out);
}